// Round 5
// baseline (301.906 us; speedup 1.0000x reference)
//
#include <hip/hip_runtime.h>
#include <hip/hip_bf16.h>
#include <cstdint>

typedef __bf16 bf16;
typedef __bf16 bf16x4 __attribute__((ext_vector_type(4)));
typedef __bf16 bf16x8 __attribute__((ext_vector_type(8)));
typedef float f32x4 __attribute__((ext_vector_type(4)));
typedef float f32x16 __attribute__((ext_vector_type(16)));

#define GK 768   // inner K for both GEMMs
#define LN_EPS 1e-5f
#define NORM_EPS 1e-12f

// ---------------- async global->LDS helper ----------------
__device__ __forceinline__ void gl_lds16(const void* g, void* l) {
  __builtin_amdgcn_global_load_lds(
      (__attribute__((address_space(1))) uint32_t*)(uintptr_t)g,
      (__attribute__((address_space(3))) uint32_t*)(uintptr_t)l,
      16, 0, 0);
}

// ---------------- block reduce (2 values, 3 waves / 192 threads) ----------------
__device__ __forceinline__ void blockReduce2w3(float& s, float& ss, float* sm) {
  #pragma unroll
  for (int o = 32; o > 0; o >>= 1) {
    s  += __shfl_down(s, o, 64);
    ss += __shfl_down(ss, o, 64);
  }
  int wave = threadIdx.x >> 6, lane = threadIdx.x & 63;
  if (lane == 0) { sm[wave] = s; sm[3 + wave] = ss; }
  __syncthreads();
  s  = sm[0] + sm[1] + sm[2];
  ss = sm[3] + sm[4] + sm[5];
  __syncthreads();
}

// ---------------- 0: tiled transpose + fp32->bf16 ----------------
__global__ __launch_bounds__(256) void transpose_cvt(const float* __restrict__ w,
                                                     bf16* __restrict__ wt,
                                                     int R, int Ncols) {
  __shared__ float tile[32][33];
  int tx = threadIdx.x & 31, ty = threadIdx.x >> 5;
  int c0 = blockIdx.x * 32, r0 = blockIdx.y * 32;
  #pragma unroll
  for (int i = 0; i < 32; i += 8)
    tile[ty + i][tx] = w[(size_t)(r0 + ty + i) * Ncols + (c0 + tx)];
  __syncthreads();
  #pragma unroll
  for (int i = 0; i < 32; i += 8)
    wt[(size_t)(c0 + ty + i) * R + (r0 + tx)] = (bf16)tile[tx][ty + i];
}

// ---------------- 1: input LayerNorm -> bf16 (192 threads) ----------
__global__ __launch_bounds__(192) void ln_in_kernel(const float* __restrict__ x,
                                                    const float* __restrict__ g,
                                                    const float* __restrict__ b,
                                                    bf16* __restrict__ h) {
  __shared__ float sm[6];
  int row = blockIdx.x, t = threadIdx.x;
  const float* xr = x + (size_t)row * 768;
  float4 v = ((const float4*)xr)[t];
  float s  = v.x + v.y + v.z + v.w;
  float ss = v.x * v.x + v.y * v.y + v.z * v.z + v.w * v.w;
  blockReduce2w3(s, ss, sm);
  float mu  = s * (1.0f / 768.0f);
  float inv = rsqrtf(ss * (1.0f / 768.0f) - mu * mu + LN_EPS);
  float4 gg = ((const float4*)g)[t];
  float4 bb = ((const float4*)b)[t];
  bf16x4 o;
  o[0] = (bf16)((v.x - mu) * inv * gg.x + bb.x);
  o[1] = (bf16)((v.y - mu) * inv * gg.y + bb.y);
  o[2] = (bf16)((v.z - mu) * inv * gg.z + bb.z);
  o[3] = (bf16)((v.w - mu) * inv * gg.w + bb.w);
  ((bf16x4*)(h + (size_t)row * 768))[t] = o;
}

// ================= 8-phase bf16 GEMM, 32x32x16 MFMA =================
// MT=4: 256x256 tile, 8 waves (2m x 4n), wave = 128x64, 8-phase/2-K-tiles.
// MT=2: 128x256 tile (GEMM2), wave = 64x64, 4-phase/2-K-tiles.
// T2 swizzle: XOR byte-bits 4-6 with row-bits 0-2 (involution, both sides).

#define SWZ(x) ((x) ^ ((((x) >> 7) & 7) << 4))

#define SB0 __builtin_amdgcn_sched_barrier(0)
#define BARS do { SB0; __builtin_amdgcn_s_barrier(); SB0; } while (0)
#define LGKM(n) do { asm volatile("s_waitcnt lgkmcnt(" #n ")" ::: "memory"); SB0; } while (0)
#define VMC(n) do { SB0; asm volatile("s_waitcnt vmcnt(" #n ")" ::: "memory"); } while (0)
#define PRIO1 __builtin_amdgcn_s_setprio(1)
#define PRIO0 __builtin_amdgcn_s_setprio(0)

// A frag: lane holds A[row = l&31][k = (l>>5)*8 + j]; rows grouped 32/m-tile
#define LDA32(buf, mh, mi, k) \
  af[mi][k] = *(const bf16x8*)((buf) + SWZ((wm * (MT * 32) + (mh) * 64 + (mi) * 32 + l31) * 128 + (k) * 32 + g16))
// B frag: lane holds B[k = (l>>5)*8 + j][col = l&31]
#define LDB32(buf, nt, k) \
  bfr[nt][k] = *(const bf16x8*)((buf) + SWZ(((nt) * 128 + wn * 32 + l31) * 128 + (k) * 32 + g16))

#define MFA(mh, mi, nt, k) \
  acc[(mh) * 2 + (mi)][nt] = __builtin_amdgcn_mfma_f32_32x32x16_bf16( \
      af[mi][k], bfr[nt][k], acc[(mh) * 2 + (mi)][nt], 0, 0, 0)
#define MF4(mh, nt, ka, kb) do { \
  MFA(mh, 0, nt, ka); MFA(mh, 1, nt, ka); MFA(mh, 0, nt, kb); MFA(mh, 1, nt, kb); } while (0)

#define RG_A01(buf, mh) do { LDA32(buf, mh, 0, 0); LDA32(buf, mh, 1, 0); LDA32(buf, mh, 0, 1); LDA32(buf, mh, 1, 1); } while (0)
#define RG_A23(buf, mh) do { LDA32(buf, mh, 0, 2); LDA32(buf, mh, 1, 2); LDA32(buf, mh, 0, 3); LDA32(buf, mh, 1, 3); } while (0)
#define RG_B0a(buf) do { LDB32(buf, 0, 0); LDB32(buf, 0, 1); } while (0)
#define RG_B0b(buf) do { LDB32(buf, 0, 2); LDB32(buf, 0, 3); } while (0)
#define RG_B1(buf)  do { LDB32(buf, 1, 0); LDB32(buf, 1, 1); LDB32(buf, 1, 2); LDB32(buf, 1, 3); } while (0)

#define STA(b, q, kt) gl_lds16(A + srcA[q] + (kt) * 64, &As_[b][(q) * 4096 + wave * 512])
#define STB(b, q, kt) gl_lds16(Bt + srcB[q] + (kt) * 64, &Bs_[b][(q) * 4096 + wave * 512])

template <int MT, bool OUT_BF16>
__global__ __launch_bounds__(512, 2) void gemm8p(const bf16* __restrict__ A,
                                                 const bf16* __restrict__ Bt,
                                                 void* __restrict__ Cv,
                                                 int Nn, int NBN) {
  __shared__ __align__(16) bf16 As_[2][MT * 4096];
  __shared__ __align__(16) bf16 Bs_[2][16384];
  const int tid = threadIdx.x;
  const int wave = tid >> 6, lane = tid & 63;
  const int l31 = lane & 31, g16 = (lane >> 5) * 16;
  const int wm = wave >> 2, wn = wave & 3;

  const int nwg = gridDim.x, bid = blockIdx.x;
  const int wg = (bid & 7) * (nwg >> 3) + (bid >> 3);
  const int rb = wg / NBN, cb = wg - rb * NBN;
  const int brow = rb * (MT * 64), bcol = cb * 256;

  uint32_t srcA[MT], srcB[4];
  #pragma unroll
  for (int q = 0; q < MT; ++q) {
    int d = q * 8192 + tid * 16;
    int a = SWZ(d);
    int r = a >> 7, c = (a & 127) >> 1;
    srcA[q] = (uint32_t)(brow + r) * GK + c;
  }
  #pragma unroll
  for (int q = 0; q < 4; ++q) {
    int d = q * 8192 + tid * 16;
    int a = SWZ(d);
    int r = a >> 7, c = (a & 127) >> 1;
    int nh = r >> 7, wnn = (r >> 5) & 3, r32 = r & 31;
    srcB[q] = (uint32_t)(bcol + wnn * 64 + nh * 32 + r32) * GK + c;
  }

  f32x16 acc[MT][2];
  #pragma unroll
  for (int m = 0; m < MT; ++m)
    #pragma unroll
    for (int n = 0; n < 2; ++n)
      #pragma unroll
      for (int r2 = 0; r2 < 16; ++r2) acc[m][n][r2] = 0.f;

  bf16x8 af[2][4], bfr[2][4];
  const char* As0 = (const char*)&As_[0][0];
  const char* As1 = (const char*)&As_[1][0];
  const char* Bs0 = (const char*)&Bs_[0][0];
  const char* Bs1 = (const char*)&Bs_[1][0];

  if constexpr (MT == 4) {
    // -------- prologue: tile0 full (8 chunks), tile1 partial (4)
    STA(0, 0, 0); STA(0, 1, 0); STA(0, 2, 0); STA(0, 3, 0);
    STB(0, 0, 0); STB(0, 1, 0); STB(0, 2, 0); STB(0, 3, 0);
    STA(1, 0, 1); STA(1, 2, 1); STB(1, 0, 1); STB(1, 1, 1);
    SB0;
    asm volatile("s_waitcnt vmcnt(4)" ::: "memory");
    __builtin_amdgcn_s_barrier();
    SB0;

    for (int j = 0; j < 6; ++j) {
      const int t1 = 2 * j + 1, t2 = 2 * j + 2, t3 = 2 * j + 3;
      // ph1: reads A(mh0)+all B of even tile; MFMA mh0 x n0
      RG_A01(As0, 0); RG_B0a(Bs0); SB0;
      RG_A23(As0, 0); RG_B0b(Bs0); SB0;
      RG_B1(Bs0); SB0;
      STA(1, 1, t1); STA(1, 3, t1);
      BARS;
      LGKM(10); PRIO1; MF4(0, 0, 0, 1);
      LGKM(4);  MF4(0, 0, 2, 3); PRIO0;
      BARS;
      // ph2: read-free; MFMA mh0 x n1
      STB(1, 2, t1); STB(1, 3, t1);
      BARS;
      LGKM(0); PRIO1; MF4(0, 1, 0, 1); MF4(0, 1, 2, 3); PRIO0;
      BARS;
      // ph3: reads A(mh1); MFMA mh1 x n0
      RG_A01(As0, 1); SB0;
      RG_A23(As0, 1); SB0;
      STA(0, 0, t2); STA(0, 2, t2);
      BARS;
      LGKM(4); PRIO1; MF4(1, 0, 0, 1);
      LGKM(0); MF4(1, 0, 2, 3); PRIO0;
      BARS;
      // ph4: read-free; MFMA mh1 x n1; counted vmcnt for odd tile
      STB(0, 0, t2); STB(0, 1, t2);
      BARS;
      PRIO1; MF4(1, 1, 0, 1); MF4(1, 1, 2, 3); PRIO0;
      VMC(4);
      BARS;
      // ph5..8: odd tile from buf1
      RG_A01(As1, 0); RG_B0a(Bs1); SB0;
      RG_A23(As1, 0); RG_B0b(Bs1); SB0;
      RG_B1(Bs1); SB0;
      STA(0, 1, t2); STA(0, 3, t2);
      BARS;
      LGKM(10); PRIO1; MF4(0, 0, 0, 1);
      LGKM(4);  MF4(0, 0, 2, 3); PRIO0;
      BARS;
      STB(0, 2, t2); STB(0, 3, t2);
      BARS;
      LGKM(0); PRIO1; MF4(0, 1, 0, 1); MF4(0, 1, 2, 3); PRIO0;
      BARS;
      RG_A01(As1, 1); SB0;
      RG_A23(As1, 1); SB0;
      STA(1, 0, t3); STA(1, 2, t3);
      BARS;
      LGKM(4); PRIO1; MF4(1, 0, 0, 1);
      LGKM(0); MF4(1, 0, 2, 3); PRIO0;
      BARS;
      STB(1, 0, t3); STB(1, 1, t3);
      BARS;
      PRIO1; MF4(1, 1, 0, 1); MF4(1, 1, 2, 3); PRIO0;
      VMC(4);
      BARS;
    }
  } else {
    // -------- MT=2 (GEMM2): 4-phase per 2 K-tiles, full-tile stage per pair
    STA(0, 0, 0); STA(0, 1, 0);
    STB(0, 0, 0); STB(0, 1, 0); STB(0, 2, 0); STB(0, 3, 0);
    SB0;
    asm volatile("s_waitcnt vmcnt(0)" ::: "memory");
    __builtin_amdgcn_s_barrier();
    SB0;

    for (int j = 0; j < 6; ++j) {
      const int t1 = 2 * j + 1, t2 = 2 * j + 2;
      // ph1: read all of even tile; stage full odd tile -> buf1; MFMA n0
      RG_A01(As0, 0); RG_B0a(Bs0); SB0;
      RG_A23(As0, 0); RG_B0b(Bs0); SB0;
      RG_B1(Bs0); SB0;
      STA(1, 0, t1); STA(1, 1, t1);
      STB(1, 0, t1); STB(1, 1, t1); STB(1, 2, t1); STB(1, 3, t1);
      BARS;
      LGKM(10); PRIO1; MF4(0, 0, 0, 1);
      LGKM(4);  MF4(0, 0, 2, 3); PRIO0;
      BARS;
      // ph2: MFMA n1; drain odd-tile stage
      BARS;
      LGKM(0); PRIO1; MF4(0, 1, 0, 1); MF4(0, 1, 2, 3); PRIO0;
      VMC(0);
      BARS;
      // ph3: read all of odd tile; stage full next-even tile -> buf0; MFMA n0
      RG_A01(As1, 0); RG_B0a(Bs1); SB0;
      RG_A23(As1, 0); RG_B0b(Bs1); SB0;
      RG_B1(Bs1); SB0;
      STA(0, 0, t2); STA(0, 1, t2);
      STB(0, 0, t2); STB(0, 1, t2); STB(0, 2, t2); STB(0, 3, t2);
      BARS;
      LGKM(10); PRIO1; MF4(0, 0, 0, 1);
      LGKM(4);  MF4(0, 0, 2, 3); PRIO0;
      BARS;
      // ph4: MFMA n1; drain
      BARS;
      LGKM(0); PRIO1; MF4(0, 1, 0, 1); MF4(0, 1, 2, 3); PRIO0;
      VMC(0);
      BARS;
    }
  }

  // -------- epilogue: C write (32x32 C/D: col=lane&31, row=(rg&3)+8*(rg>>2)+4*(lane>>5))
  #pragma unroll
  for (int mt = 0; mt < MT; ++mt) {
    #pragma unroll
    for (int nt = 0; nt < 2; ++nt) {
      int col = bcol + wn * 64 + nt * 32 + l31;
      int row0 = brow + wm * (MT * 32) + mt * 32 + (g16 >> 2);  // + 4*(lane>>5)
      #pragma unroll
      for (int rg = 0; rg < 16; ++rg) {
        int row = row0 + (rg & 3) + 8 * (rg >> 2);
        if (OUT_BF16)
          ((bf16*)Cv)[(size_t)row * Nn + col] = (bf16)acc[mt][nt][rg];
        else
          ((float*)Cv)[(size_t)row * Nn + col] = acc[mt][nt][rg];
      }
    }
  }
}

// ---------------- 3a: kv partial sums, k-norm computed inline ----------------
__global__ __launch_bounds__(256) void kv_partial(const bf16* __restrict__ qkv,
                                                  float* __restrict__ kvp) {
  __shared__ float sm[4][768];
  int b = blockIdx.x >> 5, chunk = blockIdx.x & 31;
  int wave = threadIdx.x >> 6, lane = threadIdx.x & 63;
  const bf16* base = qkv + ((size_t)(b * 4096 + chunk * 128 + wave * 32)) * 2304;
  float acc[3][4] = {};
  for (int i = 0; i < 32; ++i) {
    const bf16* kr = base + (size_t)i * 2304 + 768;
    const bf16* vr = kr + 768;
    bf16x4 k4[3], v4[3];
    #pragma unroll
    for (int c = 0; c < 3; ++c) {
      k4[c] = *(const bf16x4*)(kr + c * 256 + lane * 4);
      v4[c] = *(const bf16x4*)(vr + c * 256 + lane * 4);
    }
    float ssk = 0.f;
    #pragma unroll
    for (int c = 0; c < 3; ++c)
      #pragma unroll
      for (int j = 0; j < 4; ++j) { float kf = (float)k4[c][j]; ssk += kf * kf; }
    #pragma unroll
    for (int off = 32; off > 0; off >>= 1) ssk += __shfl_xor(ssk, off, 64);
    float wi = 1.0f / fmaxf(sqrtf(ssk), NORM_EPS);
    #pragma unroll
    for (int c = 0; c < 3; ++c)
      #pragma unroll
      for (int j = 0; j < 4; ++j)
        acc[c][j] += (float)k4[c][j] * (float)v4[c][j] * wi;
  }
  #pragma unroll
  for (int c = 0; c < 3; ++c)
    #pragma unroll
    for (int j = 0; j < 4; ++j)
      sm[wave][c * 256 + lane * 4 + j] = acc[c][j];
  __syncthreads();
  int t = threadIdx.x;
  #pragma unroll
  for (int c = 0; c < 3; ++c) {
    int e = c * 256 + t;
    kvp[(size_t)blockIdx.x * 768 + e] = sm[0][e] + sm[1][e] + sm[2][e] + sm[3][e];
  }
}

// ---------------- 3b: reduce 32 partials -> kv[8][768] ----------------
__global__ __launch_bounds__(256) void kv_reduce(const float* __restrict__ kvp,
                                                 float* __restrict__ kv) {
  int i = blockIdx.x * 256 + threadIdx.x;
  int b = i / 768, e = i - b * 768;
  float s = 0.f;
  #pragma unroll
  for (int c = 0; c < 32; ++c) s += kvp[(size_t)(b * 32 + c) * 768 + e];
  kv[i] = s;
}

// ---------------- 4: attn = phi_q * kv (q-norm inline), LN over E -> bf16 ----
__global__ __launch_bounds__(192) void attn_ln_kernel(const bf16* __restrict__ qkv,
                                                      const float* __restrict__ kv,
                                                      const float* __restrict__ g,
                                                      const float* __restrict__ b,
                                                      bf16* __restrict__ a) {
  __shared__ float sm[6];
  int row = blockIdx.x, t = threadIdx.x;
  int bt = row >> 12;
  const bf16* qr = qkv + (size_t)row * 2304;
  bf16x4 q4 = ((const bf16x4*)qr)[t];
  float q0 = (float)q4[0], q1 = (float)q4[1], q2 = (float)q4[2], q3 = (float)q4[3];
  float sq = q0 * q0 + q1 * q1 + q2 * q2 + q3 * q3, dummy = 0.f;
  blockReduce2w3(sq, dummy, sm);
  float iq = 1.0f / fmaxf(sqrtf(sq), NORM_EPS);
  float4 kv4 = ((const float4*)(kv + bt * 768))[t];
  float4 av;
  av.x = q0 * iq * kv4.x;
  av.y = q1 * iq * kv4.y;
  av.z = q2 * iq * kv4.z;
  av.w = q3 * iq * kv4.w;
  float s  = av.x + av.y + av.z + av.w;
  float ss = av.x * av.x + av.y * av.y + av.z * av.z + av.w * av.w;
  blockReduce2w3(s, ss, sm);
  float mu  = s * (1.0f / 768.0f);
  float inv = rsqrtf(ss * (1.0f / 768.0f) - mu * mu + LN_EPS);
  float4 gg = ((const float4*)g)[t];
  float4 bb = ((const float4*)b)[t];
  bf16x4 o;
  o[0] = (bf16)((av.x - mu) * inv * gg.x + bb.x);
  o[1] = (bf16)((av.y - mu) * inv * gg.y + bb.y);
  o[2] = (bf16)((av.z - mu) * inv * gg.z + bb.z);
  o[3] = (bf16)((av.w - mu) * inv * gg.w + bb.w);
  ((bf16x4*)(a + (size_t)row * 768))[t] = o;
}

// ---------------- launcher ----------------
extern "C" void kernel_launch(void* const* d_in, const int* in_sizes, int n_in,
                              void* d_out, int out_size, void* d_ws, size_t ws_size,
                              hipStream_t stream) {
  const float* x      = (const float*)d_in[0];
  const float* w_qkv  = (const float*)d_in[1];
  const float* w_proj = (const float*)d_in[2];
  const float* g_in   = (const float*)d_in[3];
  const float* b_in   = (const float*)d_in[4];
  const float* g_out  = (const float*)d_in[5];
  const float* b_out  = (const float*)d_in[6];

  char* ws = (char*)d_ws;
  bf16*  wqkvt  = (bf16*)(ws);                              // [2304][768] bf16
  bf16*  wprojt = (bf16*)(ws + 3538944);                    // [768][768]  bf16
  bf16*  h      = (bf16*)(ws + 4718592);                    // [32768][768] bf16 (reused as 'a')
  bf16*  qkv    = (bf16*)(ws + 55050240);                   // [32768][2304] bf16
  float* kvp    = (float*)(ws + 206045184);                 // [8*32][768]
  float* kv     = (float*)(ws + 206831616);                 // [8][768]

  transpose_cvt<<<dim3(2304 / 32, 768 / 32), 256, 0, stream>>>(w_qkv, wqkvt, 768, 2304);
  transpose_cvt<<<dim3(768 / 32, 768 / 32), 256, 0, stream>>>(w_proj, wprojt, 768, 768);
  ln_in_kernel<<<32768, 192, 0, stream>>>(x, g_in, b_in, h);
  gemm8p<4, true><<<128 * 9, 512, 0, stream>>>(h, wqkvt, (void*)qkv, 2304, 9);
  kv_partial<<<256, 256, 0, stream>>>(qkv, kvp);
  kv_reduce<<<24, 256, 0, stream>>>(kvp, kv);
  attn_ln_kernel<<<32768, 192, 0, stream>>>(qkv, kv, g_out, b_out, h);
  gemm8p<2, false><<<256 * 3, 512, 0, stream>>>(h, wprojt, d_out, 768, 3);
}